// Round 3
// baseline (215.647 us; speedup 1.0000x reference)
//
#include <hip/hip_runtime.h>
#include <hip/hip_bf16.h>

typedef __bf16 bf16_t;
typedef __bf16 bf16x8 __attribute__((ext_vector_type(8)));
typedef float floatx4 __attribute__((ext_vector_type(4)));

#define N_NODES 4096
#define F_IN 128
#define NUM_HEADS 4
#define D_HID 64
#define F_OUT 256  // NUM_HEADS * D_HID
#define NEG_SLOPE 0.2f

// ---------------------------------------------------------------------------
// Kernel 1: projections (f32 in, GT bf16 + el/er f32 out).
//   GT[c][j] = bf16( (h @ W_proj)[j][c] )  c < 256  (g, transposed)
//   el[h][j] = <ga[j,h,:], w_attn[:32]>   er[h][j] = <ga[j,h,:], w_attn[32:]>
// 256 blocks x 384 threads; block handles 16 nodes; thread t owns one output col.
// ---------------------------------------------------------------------------
__global__ __launch_bounds__(384) void proj_kernel(
    const float* __restrict__ hmat, const float* __restrict__ Wp,
    const float* __restrict__ Wa, const float* __restrict__ wattn,
    bf16_t* __restrict__ GT, float* __restrict__ el, float* __restrict__ er)
{
    __shared__ float hl[16][F_IN];
    const int t = threadIdx.x;
    const int j0 = blockIdx.x * 16;

    if (t < 256) {
        const int jl = t >> 4, m0 = (t & 15) * 8;
        const float4 v0 = *reinterpret_cast<const float4*>(&hmat[(size_t)(j0 + jl) * F_IN + m0]);
        const float4 v1 = *reinterpret_cast<const float4*>(&hmat[(size_t)(j0 + jl) * F_IN + m0 + 4]);
        *reinterpret_cast<float4*>(&hl[jl][m0])     = v0;
        *reinterpret_cast<float4*>(&hl[jl][m0 + 4]) = v1;
    }
    __syncthreads();

    float acc[16];
#pragma unroll
    for (int jl = 0; jl < 16; ++jl) acc[jl] = 0.f;

    const float* wptr;
    int stride;
    if (t < 256) { wptr = Wp + t;         stride = 256; }
    else         { wptr = Wa + (t - 256); stride = 128; }

    for (int m = 0; m < F_IN; m += 4) {
        const float w0 = wptr[(size_t)(m + 0) * stride];
        const float w1 = wptr[(size_t)(m + 1) * stride];
        const float w2 = wptr[(size_t)(m + 2) * stride];
        const float w3 = wptr[(size_t)(m + 3) * stride];
#pragma unroll
        for (int jl = 0; jl < 16; ++jl) {
            const float4 hv = *reinterpret_cast<const float4*>(&hl[jl][m]);
            acc[jl] = fmaf(hv.w, w3, fmaf(hv.z, w2, fmaf(hv.y, w1, fmaf(hv.x, w0, acc[jl]))));
        }
    }

    if (t < 256) {
        bf16x8 o0, o1;
#pragma unroll
        for (int q = 0; q < 8; ++q) { o0[q] = (bf16_t)acc[q]; o1[q] = (bf16_t)acc[8 + q]; }
        *reinterpret_cast<bf16x8*>(&GT[(size_t)t * N_NODES + j0])     = o0;
        *reinterpret_cast<bf16x8*>(&GT[(size_t)t * N_NODES + j0 + 8]) = o1;
    } else {
        const int ta = t - 256;          // waves 4,5; 32-lane group per head
        const int ha = ta >> 5, k = ta & 31;
        const float wl = wattn[k], wr = wattn[32 + k];
#pragma unroll
        for (int jl = 0; jl < 16; ++jl) {
            float vl = acc[jl] * wl;
            float vr = acc[jl] * wr;
#pragma unroll
            for (int s = 16; s >= 1; s >>= 1) {
                vl += __shfl_xor(vl, s, 64);
                vr += __shfl_xor(vr, s, 64);
            }
            if (k == 0) {
                el[ha * N_NODES + j0 + jl] = vl;
                er[ha * N_NODES + j0 + jl] = vr;
            }
        }
    }
}

// ---------------------------------------------------------------------------
// Kernel 2: fully fused masked-exp attention + MFMA aggregation + divide.
// Grid 256 blocks (one 16-row i-tile each) x 512 threads = 8 waves.
// Wave (hh = wave&3, half = wave>>2): head hh, j in [half*2048, half*2048+2048).
// Lane l computes p for i = i0+(l&15), j = quad*8+idx — the verified
// mfma_f32_16x16x32_bf16 A-fragment layout; B comes straight from GT rows.
// The two j-halves combine via LDS; half-0 waves divide by den and store f32.
// ---------------------------------------------------------------------------
__global__ __launch_bounds__(512) void attn_kernel(
    const float* __restrict__ adj, const bf16_t* __restrict__ GT,
    const float* __restrict__ el, const float* __restrict__ er,
    float* __restrict__ out)
{
    const int i0   = blockIdx.x * 16;
    const int tid  = threadIdx.x;
    const int wave = tid >> 6;
    const int hh   = wave & 3;          // head
    const int half = wave >> 2;         // j-half
    const int lane = tid & 63;
    const int m    = lane & 15;         // i-local (A row) / f-local (B col)
    const int quad = lane >> 4;         // k-slice selector

    const float eli = el[hh * N_NODES + i0 + m];

    floatx4 acc0 = {0.f, 0.f, 0.f, 0.f};
    floatx4 acc1 = acc0, acc2 = acc0, acc3 = acc0;
    float denp = 0.f;

    const float*  adjrow = adj + (size_t)(i0 + m) * N_NODES;
    const float*  erh    = er  + hh * N_NODES;
    const bf16_t* gtb    = GT  + (size_t)hh * D_HID * N_NODES + (size_t)m * N_NODES;

    const int jbeg = half * (N_NODES / 2);
    const int jend = jbeg + (N_NODES / 2);
    for (int j0 = jbeg; j0 < jend; j0 += 32) {
        const int jb = j0 + quad * 8;

        const float4 a0 = *reinterpret_cast<const float4*>(adjrow + jb);
        const float4 a1 = *reinterpret_cast<const float4*>(adjrow + jb + 4);
        const float pa[8] = {a0.x, a0.y, a0.z, a0.w, a1.x, a1.y, a1.z, a1.w};
        const float4 e0 = *reinterpret_cast<const float4*>(erh + jb);
        const float4 e1 = *reinterpret_cast<const float4*>(erh + jb + 4);
        const float pe[8] = {e0.x, e0.y, e0.z, e0.w, e1.x, e1.y, e1.z, e1.w};

        bf16x8 af;
        float ps = 0.f;
#pragma unroll
        for (int q = 0; q < 8; ++q) {
            float e = eli + pe[q];
            e = fmaxf(e, NEG_SLOPE * e);                       // leaky_relu
            const float p = (pa[q] >= 0.5f) ? __expf(e) : 0.f; // mask -> exp
            ps += p;
            af[q] = (bf16_t)p;
        }
        denp += ps;

        const bf16x8 g0 = *reinterpret_cast<const bf16x8*>(gtb + jb);
        const bf16x8 g1 = *reinterpret_cast<const bf16x8*>(gtb + (size_t)16 * N_NODES + jb);
        const bf16x8 g2 = *reinterpret_cast<const bf16x8*>(gtb + (size_t)32 * N_NODES + jb);
        const bf16x8 g3 = *reinterpret_cast<const bf16x8*>(gtb + (size_t)48 * N_NODES + jb);

        acc0 = __builtin_amdgcn_mfma_f32_16x16x32_bf16(af, g0, acc0, 0, 0, 0);
        acc1 = __builtin_amdgcn_mfma_f32_16x16x32_bf16(af, g1, acc1, 0, 0, 0);
        acc2 = __builtin_amdgcn_mfma_f32_16x16x32_bf16(af, g2, acc2, 0, 0, 0);
        acc3 = __builtin_amdgcn_mfma_f32_16x16x32_bf16(af, g3, acc3, 0, 0, 0);
    }

    // per-row denominator for this j-half: combine the 4 k-slices
    denp += __shfl_xor(denp, 16, 64);
    denp += __shfl_xor(denp, 32, 64);   // now: total for row i0+m (this half)

    // combine the two j-halves via LDS (stride 17 -> conflict-free)
    __shared__ float lbuf[NUM_HEADS][64][17];
    if (half == 1) {
        float* p = lbuf[hh][lane];
#pragma unroll
        for (int r = 0; r < 4; ++r) {
            p[r]      = acc0[r];
            p[4 + r]  = acc1[r];
            p[8 + r]  = acc2[r];
            p[12 + r] = acc3[r];
        }
        p[16] = denp;
    }
    __syncthreads();
    if (half == 0) {
        const float* p = lbuf[hh][lane];
#pragma unroll
        for (int r = 0; r < 4; ++r) {
            acc0[r] += p[r];
            acc1[r] += p[4 + r];
            acc2[r] += p[8 + r];
            acc3[r] += p[12 + r];
        }
        denp += p[16];

        // C/D layout: row = quad*4 + r, col = lane&15. den for row y lives in
        // lane y (any quad) -> broadcast via shfl.
#pragma unroll
        for (int r = 0; r < 4; ++r) {
            const float d  = __shfl(denp, quad * 4 + r, 64);
            const float rd = 1.0f / d;
            const int ii = i0 + quad * 4 + r;
            float* dst = out + (size_t)ii * F_OUT + hh * D_HID + m;
            dst[0]  = acc0[r] * rd;
            dst[16] = acc1[r] * rd;
            dst[32] = acc2[r] * rd;
            dst[48] = acc3[r] * rd;
        }
    }
}

// ---------------------------------------------------------------------------
extern "C" void kernel_launch(void* const* d_in, const int* in_sizes, int n_in,
                              void* d_out, int out_size, void* d_ws, size_t ws_size,
                              hipStream_t stream)
{
    const float* hmat = (const float*)d_in[0];   // (4096, 128) f32
    const float* adj  = (const float*)d_in[1];   // (4096, 4096) f32
    const float* Wp   = (const float*)d_in[2];   // (128, 256) f32
    const float* Wa   = (const float*)d_in[3];   // (128, 128) f32
    const float* watt = (const float*)d_in[4];   // (64,) f32
    float* out = (float*)d_out;                  // (4096, 256) f32 (reference dtype)

    char* ws = (char*)d_ws;
    bf16_t* GT = (bf16_t*)ws;                                  // 2 MiB
    float*  el = (float*)(ws + (2ull << 20));                  // 64 KiB
    float*  er = (float*)(ws + (2ull << 20) + (64ull << 10));  // 64 KiB

    proj_kernel<<<256, 384, 0, stream>>>(hmat, Wp, Wa, watt, GT, el, er);
    attn_kernel<<<256, 512, 0, stream>>>(adj, GT, el, er, out);
}

// Round 4
// 207.694 us; speedup vs baseline: 1.0383x; 1.0383x over previous
//
#include <hip/hip_runtime.h>
#include <hip/hip_bf16.h>

typedef __bf16 bf16_t;
typedef __bf16 bf16x4 __attribute__((ext_vector_type(4)));
typedef __bf16 bf16x8 __attribute__((ext_vector_type(8)));
typedef float floatx4 __attribute__((ext_vector_type(4)));

#define N_NODES 4096
#define F_IN 128
#define NUM_HEADS 4
#define D_HID 64
#define F_OUT 256  // NUM_HEADS * D_HID
#define NEG_SLOPE 0.2f

// ---------------------------------------------------------------------------
// Kernel 1: projections (f32 in, GT bf16 + el/er f32 out).
//   GT[c][j] = bf16( (h @ W_proj)[j][c] )  c < 256  (g, transposed)
//   el[h][j] = <ga[j,h,:], w_attn[:32]>   er[h][j] = <ga[j,h,:], w_attn[32:]>
// 1024 blocks x 384 threads; block handles 4 nodes (4 blocks/CU, 24 waves/CU).
// ---------------------------------------------------------------------------
__global__ __launch_bounds__(384) void proj_kernel(
    const float* __restrict__ hmat, const float* __restrict__ Wp,
    const float* __restrict__ Wa, const float* __restrict__ wattn,
    bf16_t* __restrict__ GT, float* __restrict__ el, float* __restrict__ er)
{
    __shared__ float hl[4][F_IN];
    const int t = threadIdx.x;
    const int j0 = blockIdx.x * 4;

    if (t < 128) {
        const int jl = t >> 5, m0 = (t & 31) * 4;
        *reinterpret_cast<float4*>(&hl[jl][m0]) =
            *reinterpret_cast<const float4*>(&hmat[(size_t)(j0 + jl) * F_IN + m0]);
    }
    __syncthreads();

    float acc[4] = {0.f, 0.f, 0.f, 0.f};

    const float* wptr;
    int stride;
    if (t < 256) { wptr = Wp + t;         stride = 256; }
    else         { wptr = Wa + (t - 256); stride = 128; }

    for (int m = 0; m < F_IN; m += 4) {
        const float w0 = wptr[(size_t)(m + 0) * stride];
        const float w1 = wptr[(size_t)(m + 1) * stride];
        const float w2 = wptr[(size_t)(m + 2) * stride];
        const float w3 = wptr[(size_t)(m + 3) * stride];
#pragma unroll
        for (int jl = 0; jl < 4; ++jl) {
            const float4 hv = *reinterpret_cast<const float4*>(&hl[jl][m]);
            acc[jl] = fmaf(hv.w, w3, fmaf(hv.z, w2, fmaf(hv.y, w1, fmaf(hv.x, w0, acc[jl]))));
        }
    }

    if (t < 256) {
        bf16x4 o;
#pragma unroll
        for (int q = 0; q < 4; ++q) o[q] = (bf16_t)acc[q];
        *reinterpret_cast<bf16x4*>(&GT[(size_t)t * N_NODES + j0]) = o;
    } else {
        const int ta = t - 256;          // waves 4,5; 32-lane group per head
        const int ha = ta >> 5, k = ta & 31;
        const float wl = wattn[k], wr = wattn[32 + k];
#pragma unroll
        for (int jl = 0; jl < 4; ++jl) {
            float vl = acc[jl] * wl;
            float vr = acc[jl] * wr;
#pragma unroll
            for (int s = 16; s >= 1; s >>= 1) {
                vl += __shfl_xor(vl, s, 64);
                vr += __shfl_xor(vr, s, 64);
            }
            if (k == 0) {
                el[ha * N_NODES + j0 + jl] = vl;
                er[ha * N_NODES + j0 + jl] = vr;
            }
        }
    }
}

// ---------------------------------------------------------------------------
// Kernel 2: fused masked-exp attention + MFMA aggregation.
// Grid (256 i-tiles, njc j-chunks) x 1024 threads = 16 waves.
// Wave w: head hh = w&3, j-quarter q = w>>2 of this block's j-chunk.
// Lane l: i = i0+(l&15), j = quad*8+idx — verified mfma A-fragment layout.
// Quarter-partials combine via LDS; njc==1 -> divide+store out directly,
// njc==2 -> store per-chunk partial numerator/denominator for reduce_kernel.
// ---------------------------------------------------------------------------
__global__ __launch_bounds__(1024) void attn_kernel(
    const float* __restrict__ adj, const bf16_t* __restrict__ GT,
    const float* __restrict__ el, const float* __restrict__ er,
    float* __restrict__ numout, float* __restrict__ den_g, int njc)
{
    const int i0   = blockIdx.x * 16;
    const int jc   = blockIdx.y;
    const int tid  = threadIdx.x;
    const int wave = tid >> 6;
    const int hh   = wave & 3;          // head
    const int q    = wave >> 2;         // j-quarter within chunk
    const int lane = tid & 63;
    const int m    = lane & 15;         // i-local (A row) / f-local (B col)
    const int quad = lane >> 4;         // k-slice selector

    const float eli = el[hh * N_NODES + i0 + m];

    floatx4 acc0 = {0.f, 0.f, 0.f, 0.f};
    floatx4 acc1 = acc0, acc2 = acc0, acc3 = acc0;
    float denp = 0.f;

    const float*  adjrow = adj + (size_t)(i0 + m) * N_NODES;
    const float*  erh    = er  + hh * N_NODES;
    const bf16_t* gtb    = GT  + (size_t)hh * D_HID * N_NODES + (size_t)m * N_NODES;

    const int jspan = N_NODES / (njc * 4);           // per-wave j extent
    const int jbeg  = jc * (N_NODES / njc) + q * jspan;
    const int jend  = jbeg + jspan;
    for (int j0 = jbeg; j0 < jend; j0 += 32) {
        const int jb = j0 + quad * 8;

        const float4 a0 = *reinterpret_cast<const float4*>(adjrow + jb);
        const float4 a1 = *reinterpret_cast<const float4*>(adjrow + jb + 4);
        const float pa[8] = {a0.x, a0.y, a0.z, a0.w, a1.x, a1.y, a1.z, a1.w};
        const float4 e0 = *reinterpret_cast<const float4*>(erh + jb);
        const float4 e1 = *reinterpret_cast<const float4*>(erh + jb + 4);
        const float pe[8] = {e0.x, e0.y, e0.z, e0.w, e1.x, e1.y, e1.z, e1.w};

        bf16x8 af;
        float ps = 0.f;
#pragma unroll
        for (int qq = 0; qq < 8; ++qq) {
            float e = eli + pe[qq];
            e = fmaxf(e, NEG_SLOPE * e);                        // leaky_relu
            const float p = (pa[qq] >= 0.5f) ? __expf(e) : 0.f; // mask -> exp
            ps += p;
            af[qq] = (bf16_t)p;
        }
        denp += ps;

        const bf16x8 g0 = *reinterpret_cast<const bf16x8*>(gtb + jb);
        const bf16x8 g1 = *reinterpret_cast<const bf16x8*>(gtb + (size_t)16 * N_NODES + jb);
        const bf16x8 g2 = *reinterpret_cast<const bf16x8*>(gtb + (size_t)32 * N_NODES + jb);
        const bf16x8 g3 = *reinterpret_cast<const bf16x8*>(gtb + (size_t)48 * N_NODES + jb);

        acc0 = __builtin_amdgcn_mfma_f32_16x16x32_bf16(af, g0, acc0, 0, 0, 0);
        acc1 = __builtin_amdgcn_mfma_f32_16x16x32_bf16(af, g1, acc1, 0, 0, 0);
        acc2 = __builtin_amdgcn_mfma_f32_16x16x32_bf16(af, g2, acc2, 0, 0, 0);
        acc3 = __builtin_amdgcn_mfma_f32_16x16x32_bf16(af, g3, acc3, 0, 0, 0);
    }

    // per-row denominator for this quarter: combine the 4 k-slices
    denp += __shfl_xor(denp, 16, 64);
    denp += __shfl_xor(denp, 32, 64);   // lane l: total for row i0+(l&15)

    // combine the 4 j-quarters via LDS (stride 17 -> conflict-free)
    __shared__ float lbuf[3][NUM_HEADS][64][17];   // 52224 B
    if (q > 0) {
        float* p = lbuf[q - 1][hh][lane];
#pragma unroll
        for (int r = 0; r < 4; ++r) {
            p[r]      = acc0[r];
            p[4 + r]  = acc1[r];
            p[8 + r]  = acc2[r];
            p[12 + r] = acc3[r];
        }
        p[16] = denp;
    }
    __syncthreads();
    if (q == 0) {
#pragma unroll
        for (int s = 0; s < 3; ++s) {
            const float* p = lbuf[s][hh][lane];
#pragma unroll
            for (int r = 0; r < 4; ++r) {
                acc0[r] += p[r];
                acc1[r] += p[4 + r];
                acc2[r] += p[8 + r];
                acc3[r] += p[12 + r];
            }
            denp += p[16];
        }

        // C/D layout: row = quad*4 + r, col = lane&15
        if (njc == 1) {
#pragma unroll
            for (int r = 0; r < 4; ++r) {
                const float d  = __shfl(denp, quad * 4 + r, 64);
                const float rd = 1.0f / d;
                const int ii = i0 + quad * 4 + r;
                float* dst = numout + (size_t)ii * F_OUT + hh * D_HID + m;
                dst[0]  = acc0[r] * rd;
                dst[16] = acc1[r] * rd;
                dst[32] = acc2[r] * rd;
                dst[48] = acc3[r] * rd;
            }
        } else {
            float* nrow = numout + (size_t)jc * ((size_t)N_NODES * F_OUT);
#pragma unroll
            for (int r = 0; r < 4; ++r) {
                const int ii = i0 + quad * 4 + r;
                float* dst = nrow + (size_t)ii * F_OUT + hh * D_HID + m;
                dst[0]  = acc0[r];
                dst[16] = acc1[r];
                dst[32] = acc2[r];
                dst[48] = acc3[r];
            }
            if (quad == 0)
                den_g[((size_t)jc * N_NODES + i0 + m) * NUM_HEADS + hh] = denp;
        }
    }
}

// ---------------------------------------------------------------------------
// Kernel 3 (njc==2 only): sum chunk partials, divide, store f32.
// ---------------------------------------------------------------------------
__global__ __launch_bounds__(256) void reduce_kernel(
    const float* __restrict__ num, const float* __restrict__ den,
    float* __restrict__ out, int njc)
{
    const int idx = blockIdx.x * 256 + threadIdx.x;  // 0 .. N*F_OUT-1
    const int i  = idx >> 8;
    const int c  = idx & 255;
    const int hh = c >> 6;
    float n = 0.f, d = 0.f;
    for (int jc = 0; jc < njc; ++jc) {
        n += num[(size_t)jc * ((size_t)N_NODES * F_OUT) + idx];
        d += den[((size_t)jc * N_NODES + i) * NUM_HEADS + hh];
    }
    out[idx] = n / d;
}

// ---------------------------------------------------------------------------
extern "C" void kernel_launch(void* const* d_in, const int* in_sizes, int n_in,
                              void* d_out, int out_size, void* d_ws, size_t ws_size,
                              hipStream_t stream)
{
    const float* hmat = (const float*)d_in[0];   // (4096, 128) f32
    const float* adj  = (const float*)d_in[1];   // (4096, 4096) f32
    const float* Wp   = (const float*)d_in[2];   // (128, 256) f32
    const float* Wa   = (const float*)d_in[3];   // (128, 128) f32
    const float* watt = (const float*)d_in[4];   // (64,) f32
    float* out = (float*)d_out;                  // (4096, 256) f32

    char* ws = (char*)d_ws;
    bf16_t* GT = (bf16_t*)ws;                                  // 2 MiB
    float*  el = (float*)(ws + (2ull << 20));                  // 64 KiB
    float*  er = (float*)(ws + (2ull << 20) + (64ull << 10));  // 64 KiB
    const size_t baseoff = (2ull << 20) + (128ull << 10);

    const size_t num_bytes = (size_t)N_NODES * F_OUT * 4;          // 4 MiB per chunk
    const size_t den_bytes = (size_t)N_NODES * NUM_HEADS * 4;      // 64 KiB per chunk
    const int njc = (ws_size >= baseoff + 2 * (num_bytes + den_bytes)) ? 2 : 1;

    float* num = (float*)(ws + baseoff);
    float* den = (float*)(ws + baseoff + (size_t)njc * num_bytes);

    proj_kernel<<<1024, 384, 0, stream>>>(hmat, Wp, Wa, watt, GT, el, er);
    if (njc == 2) {
        attn_kernel<<<dim3(256, 2), 1024, 0, stream>>>(adj, GT, el, er, num, den, 2);
        reduce_kernel<<<(N_NODES * F_OUT) / 256, 256, 0, stream>>>(num, den, out, 2);
    } else {
        attn_kernel<<<dim3(256, 1), 1024, 0, stream>>>(adj, GT, el, er, out, nullptr, 1);
    }
}

// Round 5
// 156.076 us; speedup vs baseline: 1.3817x; 1.3307x over previous
//
#include <hip/hip_runtime.h>
#include <hip/hip_bf16.h>

typedef __bf16 bf16_t;
typedef __bf16 bf16x4 __attribute__((ext_vector_type(4)));
typedef __bf16 bf16x8 __attribute__((ext_vector_type(8)));
typedef float floatx4 __attribute__((ext_vector_type(4)));

#define N_NODES 4096
#define F_IN 128
#define NUM_HEADS 4
#define D_HID 64
#define F_OUT 256  // NUM_HEADS * D_HID
#define NEG_SLOPE 0.2f

// ---------------------------------------------------------------------------
// Kernel 1: projections (f32 in; GB bf16 fragment-linear + el/er f32 out).
//   g[j][h*64+f] stored into GB so that a B-fragment (16x16x32 bf16 MFMA) is a
//   contiguous 1 KB block: GB[h][j>>5][f>>4][lane=(f&15)+16*((j>>3)&3)][j&7].
//   el[h][j] = <ga[j,h,:], w_attn[:32]>   er[h][j] = <ga[j,h,:], w_attn[32:]>
// 1024 blocks x 384 threads; block handles 4 nodes.
// ---------------------------------------------------------------------------
__global__ __launch_bounds__(384) void proj_kernel(
    const float* __restrict__ hmat, const float* __restrict__ Wp,
    const float* __restrict__ Wa, const float* __restrict__ wattn,
    bf16_t* __restrict__ GB, float* __restrict__ el, float* __restrict__ er)
{
    __shared__ float hl[4][F_IN];
    const int t = threadIdx.x;
    const int j0 = blockIdx.x * 4;

    if (t < 128) {
        const int jl = t >> 5, m0 = (t & 31) * 4;
        *reinterpret_cast<float4*>(&hl[jl][m0]) =
            *reinterpret_cast<const float4*>(&hmat[(size_t)(j0 + jl) * F_IN + m0]);
    }
    __syncthreads();

    float acc[4] = {0.f, 0.f, 0.f, 0.f};

    const float* wptr;
    int stride;
    if (t < 256) { wptr = Wp + t;         stride = 256; }
    else         { wptr = Wa + (t - 256); stride = 128; }

    for (int m = 0; m < F_IN; m += 4) {
        const float w0 = wptr[(size_t)(m + 0) * stride];
        const float w1 = wptr[(size_t)(m + 1) * stride];
        const float w2 = wptr[(size_t)(m + 2) * stride];
        const float w3 = wptr[(size_t)(m + 3) * stride];
#pragma unroll
        for (int jl = 0; jl < 4; ++jl) {
            const float4 hv = *reinterpret_cast<const float4*>(&hl[jl][m]);
            acc[jl] = fmaf(hv.w, w3, fmaf(hv.z, w2, fmaf(hv.y, w1, fmaf(hv.x, w0, acc[jl]))));
        }
    }

    if (t < 256) {
        const int h = t >> 6, f = t & 63;
        bf16x4 o;
#pragma unroll
        for (int q = 0; q < 4; ++q) o[q] = (bf16_t)acc[q];
        // fragment-linear GB element offset (bf16 elems)
        const size_t base = ((((size_t)h * 128 + (j0 >> 5)) * 4 + (f >> 4)) * 64
                             + (f & 15) + 16 * ((j0 >> 3) & 3)) * 8 + (j0 & 7);
        *reinterpret_cast<bf16x4*>(&GB[base]) = o;
    } else {
        const int ta = t - 256;          // waves 4,5; 32-lane group per head
        const int ha = ta >> 5, k = ta & 31;
        const float wl = wattn[k], wr = wattn[32 + k];
#pragma unroll
        for (int jl = 0; jl < 4; ++jl) {
            float vl = acc[jl] * wl;
            float vr = acc[jl] * wr;
#pragma unroll
            for (int s = 16; s >= 1; s >>= 1) {
                vl += __shfl_xor(vl, s, 64);
                vr += __shfl_xor(vr, s, 64);
            }
            if (k == 0) {
                el[ha * N_NODES + j0 + jl] = vl;
                er[ha * N_NODES + j0 + jl] = vr;
            }
        }
    }
}

// ---------------------------------------------------------------------------
// Kernel 2: LDS-tiled fused attention. Grid (64 i-tiles, njc) x 1024 threads.
// Per 64-j tile: phase 1 computes P[4h][64i][64j] (bf16, XOR-swizzled groups)
// from coalesced adj loads; GB tile (32 KB) staged via register double-buffer.
// Phase 2: wave (hh, mt) does MFMA on P_s x GB_s; denominator via an extra
// MFMA against an all-ones B fragment (lands in C-layout, no shuffles).
// Static LDS = 32 KB (P_s) + 32 KB (GB_s) = 64 KB.
// ---------------------------------------------------------------------------
__global__ __launch_bounds__(1024) void attn_kernel(
    const float* __restrict__ adj, const bf16_t* __restrict__ GB,
    const float* __restrict__ el, const float* __restrict__ er,
    float* __restrict__ numout, float* __restrict__ den_g,
    int njc, int ntiles)
{
    __shared__ bf16_t P_s[NUM_HEADS * 64 * 64];   // 32 KiB
    __shared__ bf16_t GB_s[32 * 512];             // 32 KiB (32 subs x 1 KB)

    const int tid = threadIdx.x;
    const int i0  = blockIdx.x * 64;
    const int jc  = blockIdx.y;
    const int jT0 = jc * ntiles * 64;

    // phase-1 identity: thread -> (block-local i, tile-local j*4)
    const int pi   = tid >> 4;            // 0..63
    const int pj4  = (tid & 15) << 2;     // 0,4,..,60
    const int glog = pj4 >> 3;            // j-group 0..7
    const int goff = pj4 & 7;             // 0 or 4
    const int psw  = ((glog ^ (pi & 7)) << 3) + goff;   // swizzled in-row offset

    // phase-2 identity
    const int wave = tid >> 6;
    const int hh   = wave >> 2;           // head
    const int mt   = wave & 3;            // m-tile (16 rows)
    const int lane = tid & 63;
    const int m    = lane & 15;
    const int quad = lane >> 4;

    float elr[NUM_HEADS];
#pragma unroll
    for (int h = 0; h < NUM_HEADS; ++h) elr[h] = el[h * N_NODES + i0 + pi];

    const float* adjp = adj + (size_t)(i0 + pi) * N_NODES + pj4;

    // GB staging: wave stages subs s0,s1; sub s=(jbL*4+h)*4+fg
    const int s0 = wave * 2, s1 = s0 + 1;
    const int s0h = (s0 >> 2) & 3, s0f = s0 & 3, s0j = s0 >> 4;
    const int s1h = (s1 >> 2) & 3, s1f = s1 & 3, s1j = s1 >> 4;

    floatx4 acc0 = {0.f, 0.f, 0.f, 0.f};
    floatx4 acc1 = acc0, acc2 = acc0, acc3 = acc0, accd = acc0;
    bf16x8 ones;
#pragma unroll
    for (int q = 0; q < 8; ++q) ones[q] = (bf16_t)1.0f;

    // prologue: prefetch tile 0 into registers
    int jb32 = jT0 >> 5;
    float4 adjv = *reinterpret_cast<const float4*>(adjp + jT0);
    float4 gbv0 = *reinterpret_cast<const float4*>(GB + ((size_t)(s0h * 128 + jb32 + s0j) * 4 + s0f) * 512 + lane * 8);
    float4 gbv1 = *reinterpret_cast<const float4*>(GB + ((size_t)(s1h * 128 + jb32 + s1j) * 4 + s1f) * 512 + lane * 8);

    for (int k = 0; k < ntiles; ++k) {
        const int jT = jT0 + k * 64;
        // ---------- phase 1 ----------
        // stage GB tile (regs -> LDS)
        *reinterpret_cast<float4*>(&GB_s[s0 * 512 + lane * 8]) = gbv0;
        *reinterpret_cast<float4*>(&GB_s[s1 * 512 + lane * 8]) = gbv1;
        // prefetch next tile into registers (overlaps both phases)
        float4 adjn, gbn0, gbn1;
        if (k + 1 < ntiles) {
            const int jbn = (jT + 64) >> 5;
            adjn = *reinterpret_cast<const float4*>(adjp + jT + 64);
            gbn0 = *reinterpret_cast<const float4*>(GB + ((size_t)(s0h * 128 + jbn + s0j) * 4 + s0f) * 512 + lane * 8);
            gbn1 = *reinterpret_cast<const float4*>(GB + ((size_t)(s1h * 128 + jbn + s1j) * 4 + s1f) * 512 + lane * 8);
        }
        // compute P for 4 heads at (pi, pj4..pj4+3)
        const bool k0 = adjv.x >= 0.5f, k1 = adjv.y >= 0.5f,
                   k2 = adjv.z >= 0.5f, k3 = adjv.w >= 0.5f;
#pragma unroll
        for (int h = 0; h < NUM_HEADS; ++h) {
            const float4 ev = *reinterpret_cast<const float4*>(er + h * N_NODES + jT + pj4);
            float e0 = elr[h] + ev.x, e1 = elr[h] + ev.y,
                  e2 = elr[h] + ev.z, e3 = elr[h] + ev.w;
            e0 = fmaxf(e0, NEG_SLOPE * e0);
            e1 = fmaxf(e1, NEG_SLOPE * e1);
            e2 = fmaxf(e2, NEG_SLOPE * e2);
            e3 = fmaxf(e3, NEG_SLOPE * e3);
            bf16x4 pv;
            pv[0] = (bf16_t)(k0 ? __expf(e0) : 0.f);
            pv[1] = (bf16_t)(k1 ? __expf(e1) : 0.f);
            pv[2] = (bf16_t)(k2 ? __expf(e2) : 0.f);
            pv[3] = (bf16_t)(k3 ? __expf(e3) : 0.f);
            *reinterpret_cast<bf16x4*>(&P_s[(h * 64 + pi) * 64 + psw]) = pv;
        }
        __syncthreads();   // P_s + GB_s ready
        // ---------- phase 2 ----------
#pragma unroll
        for (int kt = 0; kt < 2; ++kt) {
            const int gphys = (((kt * 4 + quad) ^ (m & 7)) << 3);
            const bf16x8 af = *reinterpret_cast<const bf16x8*>(
                &P_s[(hh * 64 + mt * 16 + m) * 64 + gphys]);
            accd = __builtin_amdgcn_mfma_f32_16x16x32_bf16(af, ones, accd, 0, 0, 0);
            const int bb = (kt * 16 + hh * 4) * 512 + lane * 8;
            const bf16x8 b0 = *reinterpret_cast<const bf16x8*>(&GB_s[bb]);
            const bf16x8 b1 = *reinterpret_cast<const bf16x8*>(&GB_s[bb + 512]);
            const bf16x8 b2 = *reinterpret_cast<const bf16x8*>(&GB_s[bb + 1024]);
            const bf16x8 b3 = *reinterpret_cast<const bf16x8*>(&GB_s[bb + 1536]);
            acc0 = __builtin_amdgcn_mfma_f32_16x16x32_bf16(af, b0, acc0, 0, 0, 0);
            acc1 = __builtin_amdgcn_mfma_f32_16x16x32_bf16(af, b1, acc1, 0, 0, 0);
            acc2 = __builtin_amdgcn_mfma_f32_16x16x32_bf16(af, b2, acc2, 0, 0, 0);
            acc3 = __builtin_amdgcn_mfma_f32_16x16x32_bf16(af, b3, acc3, 0, 0, 0);
        }
        if (k + 1 < ntiles) { adjv = adjn; gbv0 = gbn0; gbv1 = gbn1; }
        __syncthreads();   // P_s/GB_s consumed; safe to overwrite next iter
    }

    // epilogue: C/D row = mt*16 + quad*4 + r, col = m; den replicated per-lane in accd[r]
    const int ibase = i0 + mt * 16 + quad * 4;
    if (njc == 1) {
#pragma unroll
        for (int r = 0; r < 4; ++r) {
            const float rd = 1.0f / accd[r];
            float* dst = numout + (size_t)(ibase + r) * F_OUT + hh * D_HID + m;
            dst[0]  = acc0[r] * rd;
            dst[16] = acc1[r] * rd;
            dst[32] = acc2[r] * rd;
            dst[48] = acc3[r] * rd;
        }
    } else {
        float* nrow = numout + (size_t)jc * ((size_t)N_NODES * F_OUT);
#pragma unroll
        for (int r = 0; r < 4; ++r) {
            float* dst = nrow + (size_t)(ibase + r) * F_OUT + hh * D_HID + m;
            dst[0]  = acc0[r];
            dst[16] = acc1[r];
            dst[32] = acc2[r];
            dst[48] = acc3[r];
        }
        if (m == 0) {
#pragma unroll
            for (int r = 0; r < 4; ++r)
                den_g[((size_t)jc * N_NODES + ibase + r) * NUM_HEADS + hh] = accd[r];
        }
    }
}

// ---------------------------------------------------------------------------
// Kernel 3 (njc>1): sum chunk partials, divide, store f32.
// ---------------------------------------------------------------------------
__global__ __launch_bounds__(256) void reduce_kernel(
    const float* __restrict__ num, const float* __restrict__ den,
    float* __restrict__ out, int njc)
{
    const int idx = blockIdx.x * 256 + threadIdx.x;  // 0 .. N*F_OUT-1
    const int i  = idx >> 8;
    const int c  = idx & 255;
    const int hh = c >> 6;
    float n = 0.f, d = 0.f;
    for (int jc = 0; jc < njc; ++jc) {
        n += num[(size_t)jc * ((size_t)N_NODES * F_OUT) + idx];
        d += den[((size_t)jc * N_NODES + i) * NUM_HEADS + hh];
    }
    out[idx] = n / d;
}

// ---------------------------------------------------------------------------
extern "C" void kernel_launch(void* const* d_in, const int* in_sizes, int n_in,
                              void* d_out, int out_size, void* d_ws, size_t ws_size,
                              hipStream_t stream)
{
    const float* hmat = (const float*)d_in[0];   // (4096, 128) f32
    const float* adj  = (const float*)d_in[1];   // (4096, 4096) f32
    const float* Wp   = (const float*)d_in[2];   // (128, 256) f32
    const float* Wa   = (const float*)d_in[3];   // (128, 128) f32
    const float* watt = (const float*)d_in[4];   // (64,) f32
    float* out = (float*)d_out;                  // (4096, 256) f32

    char* ws = (char*)d_ws;
    bf16_t* GB = (bf16_t*)ws;                                  // 2 MiB
    float*  el = (float*)(ws + (2ull << 20));                  // 64 KiB
    float*  er = (float*)(ws + (2ull << 20) + (64ull << 10));  // 64 KiB
    const size_t baseoff = (2ull << 20) + (128ull << 10);

    const size_t num_bytes = (size_t)N_NODES * F_OUT * 4;          // 4 MiB per chunk
    const size_t den_bytes = (size_t)N_NODES * NUM_HEADS * 4;      // 64 KiB per chunk
    // R4 ran njc=2 -> ws_size >= ~10.4 MB guaranteed; prefer 4 if it fits.
    const int njc = (ws_size >= baseoff + 4 * (num_bytes + den_bytes)) ? 4 : 2;

    float* num = (float*)(ws + baseoff);
    float* den = (float*)(ws + baseoff + (size_t)njc * num_bytes);

    proj_kernel<<<1024, 384, 0, stream>>>(hmat, Wp, Wa, watt, GB, el, er);
    attn_kernel<<<dim3(64, njc), 1024, 0, stream>>>(adj, GB, el, er, num, den,
                                                    njc, (N_NODES / njc) / 64);
    reduce_kernel<<<(N_NODES * F_OUT) / 256, 256, 0, stream>>>(num, den, out, njc);
}